// Round 1
// baseline (135.091 us; speedup 1.0000x reference)
//
#include <hip/hip_runtime.h>
#include <math.h>

// Output flat layout (read back by harness as float32):
//   [0 .. 3L)          input_tensor (L,3): X, Y, one_hot
//   [3L .. 3L+2B)      closest_points (B,2)
//   [3L+2B .. +B)      min_index written as float values
//
// NCHUNK blocks for the partial argmin: 1024 blocks x 256 threads
// = 4096 waves = 16 waves/CU — enough TLP for the VALU-bound loop.
#define NCHUNK 1024

__global__ void copy_xy_kernel(const float2* __restrict__ mesh,
                               float* __restrict__ out0, int L) {
    int i = blockIdx.x * blockDim.x + threadIdx.x;
    if (i < L) {
        float2 p = mesh[i];
        out0[3 * i + 0] = p.x;
        out0[3 * i + 1] = p.y;
        out0[3 * i + 2] = 0.0f;   // one_hot zero; scatter of 1.0s comes later
    }
}

// thread = receiver, block = mesh chunk. All lanes read the SAME mesh point
// each iteration (wave-uniform address -> single broadcast transaction, L1-hot).
// d2 computed exactly as numpy: (x-rx)^2 + (y-ry)^2 with separate mul/mul/add
// (__fmul_rn/__fadd_rn forbid FMA contraction) so values are bit-identical to
// the reference and argmin tie-breaks cannot flip.
__global__ void partial_argmin_kernel(const float2* __restrict__ mesh,
                                      const float* __restrict__ recv,
                                      float* __restrict__ pd2,
                                      int* __restrict__ pidx,
                                      int L, int chunk) {
    const int b = threadIdx.x;   // receiver id
    const int c = blockIdx.x;    // chunk id
    const float rx = recv[3 * b + 0];
    const float ry = recv[3 * b + 1];
    int start = c * chunk;
    int end = min(start + chunk, L);

    float best = INFINITY;
    int bidx = 0x7fffffff;
    #pragma unroll 8
    for (int l = start; l < end; ++l) {
        float2 p = mesh[l];
        float dx = p.x - rx;
        float dy = p.y - ry;
        float d2 = __fadd_rn(__fmul_rn(dx, dx), __fmul_rn(dy, dy));
        // strict < keeps the FIRST (lowest-index) minimum, matching np.argmin
        if (d2 < best) { best = d2; bidx = l; }
    }
    pd2[c * blockDim.x + b] = best;
    pidx[c * blockDim.x + b] = bidx;
}

// block = receiver. Combine the NCHUNK partials with (d2, idx) lexicographic
// order (smaller d2, then smaller idx), then write all final outputs.
__global__ void reduce_finalize_kernel(const float2* __restrict__ mesh,
                                       const float* __restrict__ pd2,
                                       const int* __restrict__ pidx,
                                       float* __restrict__ out0,
                                       float* __restrict__ out1,
                                       float* __restrict__ out2,
                                       int B) {
    const int b = blockIdx.x;
    const int t = threadIdx.x;

    float best = INFINITY;
    int bidx = 0x7fffffff;
    for (int c = t; c < NCHUNK; c += blockDim.x) {
        float d2 = pd2[c * B + b];
        int   i  = pidx[c * B + b];
        if (d2 < best || (d2 == best && i < bidx)) { best = d2; bidx = i; }
    }

    __shared__ float sd[256];
    __shared__ int   si[256];
    sd[t] = best;
    si[t] = bidx;
    __syncthreads();
    for (int s = 128; s > 0; s >>= 1) {
        if (t < s) {
            float d2 = sd[t + s];
            int   i  = si[t + s];
            if (d2 < sd[t] || (d2 == sd[t] && i < si[t])) { sd[t] = d2; si[t] = i; }
        }
        __syncthreads();
    }

    if (t == 0) {
        int idx = si[0];
        out2[b] = (float)idx;                 // min_index as float (harness reads f32)
        float2 p = mesh[idx];
        out1[2 * b + 0] = p.x;                // closest_points
        out1[2 * b + 1] = p.y;
        out0[3 * (size_t)idx + 2] = 1.0f;     // one_hot scatter (dup writes of 1.0 are benign)
        if (b == 0) out0[2] = 1.0f;           // reference also sets one_hot[0] = 1
    }
}

extern "C" void kernel_launch(void* const* d_in, const int* in_sizes, int n_in,
                              void* d_out, int out_size, void* d_ws, size_t ws_size,
                              hipStream_t stream) {
    const float* mesh = (const float*)d_in[0];   // (L,2) f32
    const float* recv = (const float*)d_in[1];   // (B,3) f32
    const int L = in_sizes[0] / 2;
    const int B = in_sizes[1] / 3;               // 256

    float* out0 = (float*)d_out;                 // input_tensor (L,3)
    float* out1 = out0 + (size_t)3 * L;          // closest_points (B,2)
    float* out2 = out1 + (size_t)2 * B;          // min_index as float (B)

    float* pd2  = (float*)d_ws;                              // NCHUNK*B floats
    int*   pidx = (int*)((char*)d_ws + sizeof(float) * (size_t)NCHUNK * B);

    const int chunk = (L + NCHUNK - 1) / NCHUNK;

    copy_xy_kernel<<<(L + 255) / 256, 256, 0, stream>>>((const float2*)mesh, out0, L);
    partial_argmin_kernel<<<NCHUNK, B, 0, stream>>>((const float2*)mesh, recv,
                                                    pd2, pidx, L, chunk);
    reduce_finalize_kernel<<<B, 256, 0, stream>>>((const float2*)mesh, pd2, pidx,
                                                  out0, out1, out2, B);
}